// Round 6
// baseline (558.203 us; speedup 1.0000x reference)
//
#include <hip/hip_runtime.h>
#include <hip/hip_cooperative_groups.h>
#include <climits>

namespace cg = cooperative_groups;

#define A_N 33600
#define G_N 256
#define NC 80
#define KK 10
#define CAP 2048           // max candidates per gt (layout worst case ~1408)
#define NLOAD 8            // CAP / 256
#define GCHUNK 32
#define AB_N 132           // ceil(A_N/256)
#define NVB (AB_N * 8)     // 1056 virtual pair-blocks
#define GRID 1024
#define NTHR (GRID * 256)

// Monotone float->uint mapping: preserves total order (incl. +/-inf).
__device__ __forceinline__ unsigned int ford(float f) {
    unsigned int u = __float_as_uint(f);
    return (u & 0x80000000u) ? ~u : (u | 0x80000000u);
}

__device__ __forceinline__ unsigned long long umin64(unsigned long long a, unsigned long long b) {
    return a < b ? a : b;
}

__global__ __launch_bounds__(256, 4) void k_fused(
    const float* __restrict__ scores, const float* __restrict__ pred_b,
    const float* __restrict__ anchors, const int* __restrict__ gt_labels,
    const float* __restrict__ gt_b,
    float* __restrict__ logsum, unsigned long long* __restrict__ bucket,
    int* __restrict__ cnt, int* __restrict__ fb, int* __restrict__ assigned,
    int* __restrict__ poslist,
    float* __restrict__ out_labels, float4* __restrict__ out_bbox4,
    float* __restrict__ out_scores)
{
    cg::grid_group gridg = cg::this_grid();
    int tid = threadIdx.x;
    int t = blockIdx.x * 256 + tid;
    int lane = tid & 63;

    __shared__ float4 gbox[GCHUNK];
    __shared__ int glab[GCHUNK];
    __shared__ unsigned long long swin[4];
    __shared__ unsigned long long sel[KK];

    // ---------------- P1: init + logsum + negative defaults ----------------
    float4 z4 = make_float4(0.f, 0.f, 0.f, 0.f);
    for (int i = t; i < (A_N * 81) / 4; i += NTHR) ((float4*)out_scores)[i] = z4;
    if (t < A_N) { out_labels[t] = (float)NC; out_bbox4[t] = z4; assigned[t] = -1; }
    if (t < G_N) { cnt[t] = 0; fb[t] = INT_MAX; }
    {
        int wv = t >> 6;
        for (int row = wv; row < A_N; row += NTHR / 64) {
            const float* r = scores + (long)row * NC;
            float acc = 0.f;
            for (int c = lane; c < NC; c += 64) {
                float s = r[c];
                acc -= fmaxf(s, 0.f) + log1pf(expf(-fabsf(s)));  // -log_sigmoid(-s)
            }
            #pragma unroll
            for (int off = 32; off; off >>= 1) acc += __shfl_down(acc, off);
            if (lane == 0) logsum[row] = acc;
        }
    }
    gridg.sync();

    // ---------------- P2: pair sweep + aggregated emission + fb min --------
    for (int vb = blockIdx.x; vb < NVB; vb += GRID) {
        int ab = vb >> 3, gc = vb & 7;
        __syncthreads();                       // protect gbox from prev iter
        if (tid < GCHUNK) {
            gbox[tid] = ((const float4*)gt_b)[gc * GCHUNK + tid];
            glab[tid] = gt_labels[gc * GCHUNK + tid];
        }
        __syncthreads();

        int a = ab * 256 + tid;
        bool valid = a < A_N;
        int as = valid ? a : (A_N - 1);
        float4 pb = ((const float4*)pred_b)[as];
        float2 ap = ((const float2*)anchors)[as];
        float ls = logsum[as];
        float area_p = (pb.z - pb.x) * (pb.w - pb.y);

        for (int g = 0; g < GCHUNK; g++) {
            float4 gb = gbox[g];               // LDS broadcast
            float w = fminf(gb.z, pb.z) - fmaxf(gb.x, pb.x);
            float h = fminf(gb.w, pb.w) - fmaxf(gb.y, pb.y);
            float ovl = fmaxf(w, 0.f) * fmaxf(h, 0.f);
            bool anyov = valid && (ovl > 0.f);
            int gg = gc * GCHUNK + g;

            // fallback: lowest-index anchor with overlap>0 (wave's lowest set lane
            // has the lowest a; fire-and-forget atomicMin, no return stall)
            unsigned long long ovm = __ballot(anyov);
            if (ovm && lane == __builtin_ctzll(ovm)) atomicMin(&fb[gg], a);

            // inside == in_gt exactly (RADIUS=2.5 makes center test redundant)
            bool in_gt = (ap.x >= gb.x) && (ap.x <= gb.z) && (ap.y >= gb.y) && (ap.y <= gb.w);
            bool emit = anyov && in_gt;
            unsigned long long em = __ballot(emit);
            if (em) {
                int leader = __builtin_ctzll(em);
                int n = __builtin_popcountll(em);
                int base = 0;
                if (lane == leader) base = atomicAdd(&cnt[gg], n);  // 1 returning atomic/wave-gt
                base = __shfl(base, leader);
                if (emit) {
                    float area_g = (gb.z - gb.x) * (gb.w - gb.y);
                    float uni = area_g + area_p - ovl + 1e-6f;
                    float iou = ovl / uni;
                    float s = scores[(long)a * NC + glab[g]];
                    // log_sigmoid(s)-log_sigmoid(-s) == s (shared log1p cancels)
                    float cost = (-s - ls) + 3.0f * (-logf(iou));
                    unsigned off = __builtin_amdgcn_mbcnt_lo((unsigned)(em & 0xffffffffull), 0u);
                    off = __builtin_amdgcn_mbcnt_hi((unsigned)(em >> 32), off);
                    int slot = base + (int)off;
                    if (slot < CAP)
                        bucket[(size_t)gg * CAP + slot] =
                            ((unsigned long long)ford(cost) << 32) | (unsigned)a;
                }
            }
        }
    }
    gridg.sync();

    // ---------------- P3: per-gt top-k select + scatter --------------------
    if (blockIdx.x < G_N) {
        int g = blockIdx.x;
        int c = cnt[g];
        if (c == 0) {
            if (tid == 0) {
                int m = fb[g];
                if (m == INT_MAX) m = 0;   // no overlap anywhere -> anchor 0
                atomicMax(&assigned[m], g);
                poslist[g * KK] = m;
                #pragma unroll
                for (int i = 1; i < KK; i++) poslist[g * KK + i] = -1;
            }
        } else {
            int wid = tid >> 6;
            int k = c < KK ? c : KK;
            int nreal = c < CAP ? c : CAP;
            const unsigned long long* bk = bucket + (size_t)g * CAP;
            unsigned long long kv[NLOAD];
            #pragma unroll
            for (int i = 0; i < NLOAD; i++) {
                int idx = tid + i * 256;
                kv[i] = (idx < nreal) ? bk[idx] : ~0ull;
            }
            for (int it = 0; it < k; it++) {
                unsigned long long m = kv[0];
                #pragma unroll
                for (int i = 1; i < NLOAD; i++) m = umin64(m, kv[i]);
                #pragma unroll
                for (int off = 32; off; off >>= 1) m = umin64(m, __shfl_down(m, off));
                if (lane == 0) swin[wid] = m;
                __syncthreads();
                if (tid == 0)
                    sel[it] = umin64(umin64(swin[0], swin[1]), umin64(swin[2], swin[3]));
                __syncthreads();
                unsigned long long win = sel[it];
                #pragma unroll
                for (int i = 0; i < NLOAD; i++) if (kv[i] == win) kv[i] = ~0ull; // unique
            }
            if (tid < KK) poslist[g * KK + tid] = (tid < k) ? (int)(sel[tid] & 0xffffffffu) : -1;
            if (tid < k) atomicMax(&assigned[(int)(sel[tid] & 0xffffffffu)], g);
        }
    }
    gridg.sync();

    // ---------------- P4: positives-only output fix-up ---------------------
    if (t < G_N * KK) {
        int e = poslist[t];
        if (e >= 0) {
            int a = e;
            int g2 = assigned[a];              // final (post grid sync); >= 0
            int label = gt_labels[g2];
            float4 gb = ((const float4*)gt_b)[g2];
            float4 pbx = ((const float4*)pred_b)[a];
            float w = fminf(gb.z, pbx.z) - fmaxf(gb.x, pbx.x);
            float h = fminf(gb.w, pbx.w) - fmaxf(gb.y, pbx.y);
            float ovl = fmaxf(w, 0.f) * fmaxf(h, 0.f);
            float area_g = (gb.z - gb.x) * (gb.w - gb.y);
            float area_p = (pbx.z - pbx.x) * (pbx.w - pbx.y);
            float uni = area_g + area_p - ovl + 1e-6f;
            float iou = ovl / uni;
            out_labels[a] = (float)label;      // duplicates write identical values
            out_bbox4[a] = gb;
            out_scores[(long)a * (NC + 1) + label] = iou;
        }
    }
}

extern "C" void kernel_launch(void* const* d_in, const int* in_sizes, int n_in,
                              void* d_out, int out_size, void* d_ws, size_t ws_size,
                              hipStream_t stream) {
    const float* pred_scores   = (const float*)d_in[0];
    const float* pred_bboxes   = (const float*)d_in[1];
    const float* anchor_points = (const float*)d_in[2];
    const int*   gt_labels     = (const int*)d_in[3];
    const float* gt_bboxes     = (const float*)d_in[4];

    char* ws = (char*)d_ws;
    unsigned long long* bucket = (unsigned long long*)ws;         // G*CAP u64 (8B-aligned first)
    size_t off = (size_t)G_N * CAP * 8;                           // 4 MiB
    int*   assigned = (int*)(ws + off);   off += (size_t)A_N * 4;
    int*   cnt      = (int*)(ws + off);   off += (size_t)G_N * 4;
    int*   fb       = (int*)(ws + off);   off += (size_t)G_N * 4;
    int*   poslist  = (int*)(ws + off);   off += (size_t)G_N * KK * 4;
    float* logsum   = (float*)(ws + off);

    float*  out_labels = (float*)d_out;                 // A
    float4* out_bbox4  = (float4*)(out_labels + A_N);   // A float4
    float*  out_scores = out_labels + 5 * (size_t)A_N;  // A*81

    void* args[] = {
        (void*)&pred_scores, (void*)&pred_bboxes, (void*)&anchor_points,
        (void*)&gt_labels, (void*)&gt_bboxes,
        (void*)&logsum, (void*)&bucket, (void*)&cnt, (void*)&fb,
        (void*)&assigned, (void*)&poslist,
        (void*)&out_labels, (void*)&out_bbox4, (void*)&out_scores
    };
    hipLaunchCooperativeKernel((const void*)k_fused, dim3(GRID), dim3(256),
                               args, 0, stream);
}

// Round 7
// 191.221 us; speedup vs baseline: 2.9192x; 2.9192x over previous
//
#include <hip/hip_runtime.h>
#include <climits>

#define A_N 33600
#define G_N 256
#define NC 80
#define KK 10
#define CAP 2048           // max candidates per gt (layout worst case ~1408)
#define NLOAD 8            // CAP / 256
#define GCHUNK 32
#define NCHUNK (G_N / GCHUNK)   // 8

// Monotone float->uint mapping: preserves total order (incl. +/-inf).
__device__ __forceinline__ unsigned int ford(float f) {
    unsigned int u = __float_as_uint(f);
    return (u & 0x80000000u) ? ~u : (u | 0x80000000u);
}

__device__ __forceinline__ unsigned long long umin64(unsigned long long a, unsigned long long b) {
    return a < b ? a : b;
}

// Fused init: per-anchor logsum (one wave per anchor) + cnt=0 + fb=INT_MAX +
// assigned=-1 + full negative-default outputs (labels=80, bbox=0, scores=0).
// Grid: 8400 blocks x 256 = 33600 waves.
__global__ __launch_bounds__(256) void k_init(
    const float* __restrict__ scores, float* __restrict__ logsum,
    int* __restrict__ cnt, int* __restrict__ fb, int* __restrict__ assigned,
    float* __restrict__ out_labels, float4* __restrict__ out_bbox4,
    float4* __restrict__ out_scores4)
{
    int t = blockIdx.x * 256 + threadIdx.x;
    int wv = t >> 6, lane = t & 63;
    float4 z4 = make_float4(0.f, 0.f, 0.f, 0.f);

    if (t < G_N) { cnt[t] = 0; fb[t] = INT_MAX; }
    if (t < A_N) { assigned[t] = -1; out_labels[t] = (float)NC; out_bbox4[t] = z4; }
    if (t < (A_N * 81) / 4) out_scores4[t] = z4;

    // logsum[a] = sum_c log_sigmoid(-s[a,c]) = -sum_c (max(s,0) + log1p(exp(-|s|)))
    const float* row = scores + (long)wv * NC;
    float acc = 0.f;
    for (int c = lane; c < NC; c += 64) {
        float s = row[c];
        acc -= (fmaxf(s, 0.f) + log1pf(expf(-fabsf(s))));
    }
    #pragma unroll
    for (int off = 32; off > 0; off >>= 1) acc += __shfl_down(acc, off);
    if (lane == 0) logsum[wv] = acc;
}

// Anchor-parallel sparse emission, gt-chunked for occupancy:
// grid (132 anchor-blocks, 8 gt-chunks) x 256 threads.
// Per (wave,gt): aggregated bucket emission (1 returning atomicAdd) and
// fallback atomicMin of the lowest-index anchor with overlap>0.
// inside == in_gt exactly (RADIUS=2.5 makes the center test redundant).
__global__ __launch_bounds__(256) void k_pairs(
    const float* __restrict__ scores, const float* __restrict__ pred_b,
    const float* __restrict__ anchors, const int* __restrict__ gt_labels,
    const float* __restrict__ gt_b, const float* __restrict__ logsum,
    unsigned long long* __restrict__ bucket, int* __restrict__ cnt,
    int* __restrict__ fb)
{
    __shared__ float4 gbox[GCHUNK];
    __shared__ int glab[GCHUNK];
    int tid = threadIdx.x;
    int lane = tid & 63;
    int gc = blockIdx.y;
    if (tid < GCHUNK) {
        gbox[tid] = ((const float4*)gt_b)[gc * GCHUNK + tid];
        glab[tid] = gt_labels[gc * GCHUNK + tid];
    }
    __syncthreads();

    int a = blockIdx.x * 256 + tid;
    bool valid = a < A_N;
    int as = valid ? a : (A_N - 1);
    float4 pb = ((const float4*)pred_b)[as];
    float2 ap = ((const float2*)anchors)[as];
    float ls = logsum[as];
    float area_p = (pb.z - pb.x) * (pb.w - pb.y);

    for (int g = 0; g < GCHUNK; g++) {
        float4 gb = gbox[g];               // LDS broadcast
        float w = fminf(gb.z, pb.z) - fmaxf(gb.x, pb.x);
        float h = fminf(gb.w, pb.w) - fmaxf(gb.y, pb.y);
        float ovl = fmaxf(w, 0.f) * fmaxf(h, 0.f);
        bool anyov = valid && (ovl > 0.f);
        int gg = gc * GCHUNK + g;

        // fallback candidate: lowest lane == lowest anchor index in this wave
        unsigned long long ovm = __ballot(anyov);
        if (ovm && lane == __builtin_ctzll(ovm)) atomicMin(&fb[gg], a);

        bool in_gt = (ap.x >= gb.x) && (ap.x <= gb.z) && (ap.y >= gb.y) && (ap.y <= gb.w);
        bool emit = anyov && in_gt;
        unsigned long long em = __ballot(emit);
        if (em) {
            int leader = __builtin_ctzll(em);
            int n = __builtin_popcountll(em);
            int base = 0;
            if (lane == leader) base = atomicAdd(&cnt[gg], n);   // 1 returning atomic/wave-gt
            base = __shfl(base, leader);
            if (emit) {
                float area_g = (gb.z - gb.x) * (gb.w - gb.y);
                float uni = area_g + area_p - ovl + 1e-6f;
                float iou = ovl / uni;
                float s = scores[(long)a * NC + glab[g]];
                // log_sigmoid(s)-log_sigmoid(-s) == s (shared log1p term cancels)
                float cost = (-s - ls) + 3.0f * (-logf(iou));
                unsigned off = __builtin_amdgcn_mbcnt_lo((unsigned)(em & 0xffffffffull), 0u);
                off = __builtin_amdgcn_mbcnt_hi((unsigned)(em >> 32), off);
                int slot = base + (int)off;
                if (slot < CAP)
                    bucket[(size_t)gg * CAP + slot] =
                        ((unsigned long long)ford(cost) << 32) | (unsigned)a;
            }
        }
    }
}

// One block per gt: select min(cnt,10) smallest keys (exact, order-independent),
// scatter atomicMax into assigned, record poslist. cnt==0: winner from fb[g]
// (lowest-index anchor with overlap>0: all iou>0 anchors tie at cost exactly
// 1e10 -> index tiebreak; iou==0 is +inf).
__global__ __launch_bounds__(256) void k_select(
    const unsigned long long* __restrict__ bucket, const int* __restrict__ cnt_arr,
    const int* __restrict__ fb, int* __restrict__ assigned, int* __restrict__ poslist)
{
    int g = blockIdx.x, tid = threadIdx.x;
    int wid = tid >> 6, lane = tid & 63;
    __shared__ unsigned long long swin[4];
    __shared__ unsigned long long sel[KK];

    int cnt = cnt_arr[g];

    if (cnt == 0) {
        if (tid == 0) {
            int m = fb[g];
            if (m == INT_MAX) m = 0;   // no overlapping anchor at all -> index 0
            atomicMax(&assigned[m], g);
            poslist[g * KK] = m;
            #pragma unroll
            for (int i = 1; i < KK; i++) poslist[g * KK + i] = -1;
        }
        return;
    }

    int k = cnt < KK ? cnt : KK;
    int nreal = cnt < CAP ? cnt : CAP;
    const unsigned long long* bk = bucket + (size_t)g * CAP;
    unsigned long long kv[NLOAD];
    #pragma unroll
    for (int i = 0; i < NLOAD; i++) {
        int idx = tid + i * 256;
        kv[i] = (idx < nreal) ? bk[idx] : ~0ull;
    }

    for (int it = 0; it < k; it++) {
        unsigned long long m = kv[0];
        #pragma unroll
        for (int i = 1; i < NLOAD; i++) m = umin64(m, kv[i]);
        #pragma unroll
        for (int off = 32; off; off >>= 1) m = umin64(m, __shfl_down(m, off));
        if (lane == 0) swin[wid] = m;
        __syncthreads();
        if (tid == 0)
            sel[it] = umin64(umin64(swin[0], swin[1]), umin64(swin[2], swin[3]));
        __syncthreads();
        unsigned long long win = sel[it];
        #pragma unroll
        for (int i = 0; i < NLOAD; i++) if (kv[i] == win) kv[i] = ~0ull;  // unique key
    }

    if (tid < KK) poslist[g * KK + tid] = (tid < k) ? (int)(sel[tid] & 0xffffffffu) : -1;
    if (tid < k) atomicMax(&assigned[(int)(sel[tid] & 0xffffffffu)], g);
}

// Positives-only output fix-up: <=2560 candidate anchors; assigned[] is final
// (stream order). Duplicate entries write identical values -> deterministic.
__global__ __launch_bounds__(256) void k_fix(
    const int* __restrict__ poslist, const int* __restrict__ assigned,
    const int* __restrict__ gt_labels, const float* __restrict__ gt_b,
    const float* __restrict__ pred_b,
    float* __restrict__ out_labels, float4* __restrict__ out_bbox4,
    float* __restrict__ out_scores)
{
    int t = blockIdx.x * 256 + threadIdx.x;
    if (t >= G_N * KK) return;
    int a = poslist[t];
    if (a < 0) return;
    int g = assigned[a];               // final; >= 0 since a was scattered by someone
    int label = gt_labels[g];
    float4 gb = ((const float4*)gt_b)[g];
    float4 pb = ((const float4*)pred_b)[a];
    float w = fminf(gb.z, pb.z) - fmaxf(gb.x, pb.x);
    float h = fminf(gb.w, pb.w) - fmaxf(gb.y, pb.y);
    float ovl = fmaxf(w, 0.f) * fmaxf(h, 0.f);
    float area_g = (gb.z - gb.x) * (gb.w - gb.y);
    float area_p = (pb.z - pb.x) * (pb.w - pb.y);
    float uni = area_g + area_p - ovl + 1e-6f;
    float iou = ovl / uni;
    out_labels[a] = (float)label;
    out_bbox4[a] = gb;
    out_scores[(long)a * (NC + 1) + label] = iou;
}

extern "C" void kernel_launch(void* const* d_in, const int* in_sizes, int n_in,
                              void* d_out, int out_size, void* d_ws, size_t ws_size,
                              hipStream_t stream) {
    const float* pred_scores   = (const float*)d_in[0];
    const float* pred_bboxes   = (const float*)d_in[1];
    const float* anchor_points = (const float*)d_in[2];
    const int*   gt_labels     = (const int*)d_in[3];
    const float* gt_bboxes     = (const float*)d_in[4];

    char* ws = (char*)d_ws;
    unsigned long long* bucket = (unsigned long long*)ws;         // G*CAP u64 (8B-aligned first)
    size_t off = (size_t)G_N * CAP * 8;                           // 4 MiB
    int*   assigned = (int*)(ws + off);   off += (size_t)A_N * 4;
    int*   cnt      = (int*)(ws + off);   off += (size_t)G_N * 4;
    int*   fb       = (int*)(ws + off);   off += (size_t)G_N * 4;
    int*   poslist  = (int*)(ws + off);   off += (size_t)G_N * KK * 4;
    float* logsum   = (float*)(ws + off);

    float*  out_labels = (float*)d_out;                 // A
    float4* out_bbox4  = (float4*)(out_labels + A_N);   // A float4 (16B-aligned)
    float*  out_scores = out_labels + 5 * (size_t)A_N;  // A*81 (16B-aligned)

    k_init<<<A_N / 4, 256, 0, stream>>>(pred_scores, logsum, cnt, fb, assigned,
                                        out_labels, out_bbox4, (float4*)out_scores);
    dim3 pg((A_N + 255) / 256, NCHUNK);
    k_pairs<<<pg, 256, 0, stream>>>(pred_scores, pred_bboxes, anchor_points,
                                    gt_labels, gt_bboxes, logsum, bucket, cnt, fb);
    k_select<<<G_N, 256, 0, stream>>>(bucket, cnt, fb, assigned, poslist);
    k_fix<<<(G_N * KK + 255) / 256, 256, 0, stream>>>(poslist, assigned, gt_labels,
                                                      gt_bboxes, pred_bboxes,
                                                      out_labels, out_bbox4, out_scores);
}

// Round 8
// 45.393 us; speedup vs baseline: 12.2972x; 4.2126x over previous
//
#include <hip/hip_runtime.h>
#include <climits>

#define A_N 33600
#define G_N 256
#define NC 80
#define KK 10
#define CAP 2048           // max candidates per gt (layout worst case ~1408)
#define NLOAD 8            // CAP / 256
#define GCHUNK 32
#define NCHUNK (G_N / GCHUNK)   // 8
#define FBSEG 16
#define FBSEG_LEN (A_N / FBSEG) // 2100
#define INIT_BLKS (A_N / 4)     // 8400 (one wave per anchor for logsum)
#define FB_BLKS (G_N * FBSEG)   // 4096

// Monotone float->uint mapping: preserves total order (incl. +/-inf).
__device__ __forceinline__ unsigned int ford(float f) {
    unsigned int u = __float_as_uint(f);
    return (u & 0x80000000u) ? ~u : (u | 0x80000000u);
}

__device__ __forceinline__ unsigned long long umin64(unsigned long long a, unsigned long long b) {
    return a < b ? a : b;
}

// Fused init, two block roles (no cross-role races):
//  blocks [0, INIT_BLKS): logsum (one wave/anchor) + cnt=0 + assigned=-1 +
//    negative-default outputs (labels=80, bbox=0, scores=0).
//  blocks [INIT_BLKS, +FB_BLKS): fallback pre-scan — block (g,seg) plain-stores
//    min{a in segment : overlap(pred[a], gt[g]) > 0} into fbseg[g*16+seg].
//    (race-free: each block owns one slot; no init required.)
__global__ __launch_bounds__(256) void k_init(
    const float* __restrict__ scores, const float* __restrict__ pred_b,
    const float* __restrict__ gt_b,
    float* __restrict__ logsum, int* __restrict__ cnt, int* __restrict__ assigned,
    int* __restrict__ fbseg,
    float* __restrict__ out_labels, float4* __restrict__ out_bbox4,
    float4* __restrict__ out_scores4)
{
    int b = blockIdx.x, tid = threadIdx.x;
    int lane = tid & 63, wid = tid >> 6;

    if (b >= INIT_BLKS) {           // ---- fallback segment scan ----
        int idx = b - INIT_BLKS;
        int g = idx >> 4, seg = idx & (FBSEG - 1);
        __shared__ int smin[4];
        float4 gb = ((const float4*)gt_b)[g];
        int best = INT_MAX;
        int a0 = seg * FBSEG_LEN;
        for (int a = a0 + tid; a < a0 + FBSEG_LEN; a += 256) {
            float4 pb = ((const float4*)pred_b)[a];
            float w = fminf(gb.z, pb.z) - fmaxf(gb.x, pb.x);
            float h = fminf(gb.w, pb.w) - fmaxf(gb.y, pb.y);
            if (w > 0.f && h > 0.f && a < best) best = a;
        }
        #pragma unroll
        for (int off = 32; off; off >>= 1) best = min(best, __shfl_down(best, off));
        if (lane == 0) smin[wid] = best;
        __syncthreads();
        if (tid == 0)
            fbseg[g * FBSEG + seg] = min(min(smin[0], smin[1]), min(smin[2], smin[3]));
        return;
    }

    // ---- init + logsum ----
    int t = b * 256 + tid;
    float4 z4 = make_float4(0.f, 0.f, 0.f, 0.f);
    if (t < G_N) cnt[t] = 0;
    if (t < A_N) { assigned[t] = -1; out_labels[t] = (float)NC; out_bbox4[t] = z4; }
    if (t < (A_N * 81) / 4) out_scores4[t] = z4;

    // logsum[a] = sum_c log_sigmoid(-s[a,c]) = -sum_c (max(s,0) + log1p(exp(-|s|)))
    int wv = t >> 6;
    const float* row = scores + (long)wv * NC;
    float acc = 0.f;
    for (int c = lane; c < NC; c += 64) {
        float s = row[c];
        acc -= (fmaxf(s, 0.f) + log1pf(expf(-fabsf(s))));
    }
    #pragma unroll
    for (int off = 32; off > 0; off >>= 1) acc += __shfl_down(acc, off);
    if (lane == 0) logsum[wv] = acc;
}

// Anchor-parallel sparse emission, gt-chunked for occupancy (round-5 body:
// early continue; per-thread atomicAdd — compiler wave-aggregates uniform-address
// increments automatically). grid (132, 8) x 256.
// inside == in_gt exactly (RADIUS=2.5 makes the center test redundant).
__global__ __launch_bounds__(256) void k_pairs(
    const float* __restrict__ scores, const float* __restrict__ pred_b,
    const float* __restrict__ anchors, const int* __restrict__ gt_labels,
    const float* __restrict__ gt_b, const float* __restrict__ logsum,
    unsigned long long* __restrict__ bucket, int* __restrict__ cnt)
{
    __shared__ float4 gbox[GCHUNK];
    __shared__ int glab[GCHUNK];
    int tid = threadIdx.x;
    int gc = blockIdx.y;
    if (tid < GCHUNK) {
        gbox[tid] = ((const float4*)gt_b)[gc * GCHUNK + tid];
        glab[tid] = gt_labels[gc * GCHUNK + tid];
    }
    __syncthreads();

    int a = blockIdx.x * 256 + tid;
    if (a >= A_N) return;

    float4 pb = ((const float4*)pred_b)[a];
    float2 ap = ((const float2*)anchors)[a];
    float area_p = (pb.z - pb.x) * (pb.w - pb.y);
    float ls = logsum[a];

    #pragma unroll 4
    for (int g = 0; g < GCHUNK; g++) {
        float4 gb = gbox[g];               // LDS broadcast
        bool in_gt = (ap.x >= gb.x) & (ap.x <= gb.z) & (ap.y >= gb.y) & (ap.y <= gb.w);
        if (!in_gt) continue;

        float ltx = fmaxf(gb.x, pb.x), lty = fmaxf(gb.y, pb.y);
        float rbx = fminf(gb.z, pb.z), rby = fminf(gb.w, pb.w);
        float w = fmaxf(rbx - ltx, 0.f), h = fmaxf(rby - lty, 0.f);
        float overlap = w * h;
        if (!(overlap > 0.f)) continue;    // inside & iou==0 -> +inf, never selected

        int gg = gc * GCHUNK + g;
        float area_g = (gb.z - gb.x) * (gb.w - gb.y);
        float uni = area_g + area_p - overlap + 1e-6f;
        float iou = overlap / uni;
        float s = scores[(long)a * NC + glab[g]];
        // log_sigmoid(s)-log_sigmoid(-s) == s (shared log1p term cancels)
        float cost = (-s - ls) + 3.0f * (-logf(iou));
        unsigned long long key = ((unsigned long long)ford(cost) << 32) | (unsigned)a;

        int slot = atomicAdd(&cnt[gg], 1);
        if (slot < CAP) bucket[(size_t)gg * CAP + slot] = key;
    }
}

// One block per gt: select min(cnt,10) smallest keys (exact, order-independent),
// scatter atomicMax into assigned, record poslist. cnt==0: winner = min over the
// 16 precomputed fbseg slots (lowest-index anchor with overlap>0: all iou>0
// anchors tie at cost exactly 1e10 -> index tiebreak; iou==0 is +inf).
__global__ __launch_bounds__(256) void k_select(
    const unsigned long long* __restrict__ bucket, const int* __restrict__ cnt_arr,
    const int* __restrict__ fbseg, int* __restrict__ assigned, int* __restrict__ poslist)
{
    int g = blockIdx.x, tid = threadIdx.x;
    int wid = tid >> 6, lane = tid & 63;
    __shared__ unsigned long long swin[4];
    __shared__ unsigned long long sel[KK];

    int cnt = cnt_arr[g];

    if (cnt == 0) {
        int v = (tid < FBSEG) ? fbseg[g * FBSEG + tid] : INT_MAX;
        if (tid < 64) {
            #pragma unroll
            for (int off = 8; off; off >>= 1) v = min(v, __shfl_down(v, off));
        }
        if (tid == 0) {
            if (v == INT_MAX) v = 0;   // no overlapping anchor at all -> index 0
            atomicMax(&assigned[v], g);
            poslist[g * KK] = v;
            #pragma unroll
            for (int i = 1; i < KK; i++) poslist[g * KK + i] = -1;
        }
        return;
    }

    int k = cnt < KK ? cnt : KK;
    int nreal = cnt < CAP ? cnt : CAP;
    const unsigned long long* bk = bucket + (size_t)g * CAP;
    unsigned long long kv[NLOAD];
    #pragma unroll
    for (int i = 0; i < NLOAD; i++) {
        int idx = tid + i * 256;
        kv[i] = (idx < nreal) ? bk[idx] : ~0ull;
    }

    for (int it = 0; it < k; it++) {
        unsigned long long m = kv[0];
        #pragma unroll
        for (int i = 1; i < NLOAD; i++) m = umin64(m, kv[i]);
        #pragma unroll
        for (int off = 32; off; off >>= 1) m = umin64(m, __shfl_down(m, off));
        if (lane == 0) swin[wid] = m;
        __syncthreads();
        if (tid == 0)
            sel[it] = umin64(umin64(swin[0], swin[1]), umin64(swin[2], swin[3]));
        __syncthreads();
        unsigned long long win = sel[it];
        #pragma unroll
        for (int i = 0; i < NLOAD; i++) if (kv[i] == win) kv[i] = ~0ull;  // unique key
    }

    if (tid < KK) poslist[g * KK + tid] = (tid < k) ? (int)(sel[tid] & 0xffffffffu) : -1;
    if (tid < k) atomicMax(&assigned[(int)(sel[tid] & 0xffffffffu)], g);
}

// Positives-only output fix-up: <=2560 candidate anchors; assigned[] is final
// (stream order). Duplicate entries write identical values -> deterministic.
__global__ __launch_bounds__(256) void k_fix(
    const int* __restrict__ poslist, const int* __restrict__ assigned,
    const int* __restrict__ gt_labels, const float* __restrict__ gt_b,
    const float* __restrict__ pred_b,
    float* __restrict__ out_labels, float4* __restrict__ out_bbox4,
    float* __restrict__ out_scores)
{
    int t = blockIdx.x * 256 + threadIdx.x;
    if (t >= G_N * KK) return;
    int a = poslist[t];
    if (a < 0) return;
    int g = assigned[a];               // final; >= 0 since a was scattered by someone
    int label = gt_labels[g];
    float4 gb = ((const float4*)gt_b)[g];
    float4 pb = ((const float4*)pred_b)[a];
    float w = fminf(gb.z, pb.z) - fmaxf(gb.x, pb.x);
    float h = fminf(gb.w, pb.w) - fmaxf(gb.y, pb.y);
    float ovl = fmaxf(w, 0.f) * fmaxf(h, 0.f);
    float area_g = (gb.z - gb.x) * (gb.w - gb.y);
    float area_p = (pb.z - pb.x) * (pb.w - pb.y);
    float uni = area_g + area_p - ovl + 1e-6f;
    float iou = ovl / uni;
    out_labels[a] = (float)label;
    out_bbox4[a] = gb;
    out_scores[(long)a * (NC + 1) + label] = iou;
}

extern "C" void kernel_launch(void* const* d_in, const int* in_sizes, int n_in,
                              void* d_out, int out_size, void* d_ws, size_t ws_size,
                              hipStream_t stream) {
    const float* pred_scores   = (const float*)d_in[0];
    const float* pred_bboxes   = (const float*)d_in[1];
    const float* anchor_points = (const float*)d_in[2];
    const int*   gt_labels     = (const int*)d_in[3];
    const float* gt_bboxes     = (const float*)d_in[4];

    char* ws = (char*)d_ws;
    unsigned long long* bucket = (unsigned long long*)ws;         // G*CAP u64 (8B-aligned first)
    size_t off = (size_t)G_N * CAP * 8;                           // 4 MiB
    int*   assigned = (int*)(ws + off);   off += (size_t)A_N * 4;
    int*   cnt      = (int*)(ws + off);   off += (size_t)G_N * 4;
    int*   fbseg    = (int*)(ws + off);   off += (size_t)G_N * FBSEG * 4;
    int*   poslist  = (int*)(ws + off);   off += (size_t)G_N * KK * 4;
    float* logsum   = (float*)(ws + off);

    float*  out_labels = (float*)d_out;                 // A
    float4* out_bbox4  = (float4*)(out_labels + A_N);   // A float4 (16B-aligned)
    float*  out_scores = out_labels + 5 * (size_t)A_N;  // A*81 (16B-aligned)

    k_init<<<INIT_BLKS + FB_BLKS, 256, 0, stream>>>(
        pred_scores, pred_bboxes, gt_bboxes, logsum, cnt, assigned, fbseg,
        out_labels, out_bbox4, (float4*)out_scores);
    dim3 pg((A_N + 255) / 256, NCHUNK);
    k_pairs<<<pg, 256, 0, stream>>>(pred_scores, pred_bboxes, anchor_points,
                                    gt_labels, gt_bboxes, logsum, bucket, cnt);
    k_select<<<G_N, 256, 0, stream>>>(bucket, cnt, fbseg, assigned, poslist);
    k_fix<<<(G_N * KK + 255) / 256, 256, 0, stream>>>(poslist, assigned, gt_labels,
                                                      gt_bboxes, pred_bboxes,
                                                      out_labels, out_bbox4, out_scores);
}